// Round 6
// baseline (118.804 us; speedup 1.0000x reference)
//
#include <hip/hip_runtime.h>

#define NPTS 4096
#define NBATCH 16
#define THREADS 256
#define QP 16      // queries per thread (kernel A)
#define NBLK_B 512 // kernel B blocks

// Chamfer, fp32, B=16, N=M=4096, d=3. Two dispatches:
//  A (TC=32): grid (32,16,2)=1024 blocks -> 4 blocks/CU, 4 waves/SIMD.
//     Block stages 128 targets (2 KB LDS) as (x,y,z,0.5|t|^2); each thread owns
//     16 queries -> 256 VALU ops per 4 broadcast ds_read_b128. Register
//     double-buffer: group n+4 loaded before computing group n, so ds_read
//     latency (~120cyc) is covered by the 512-cyc compute block. 4 waves/SIMD
//     (r2->r4 showed 1->2 waves = 1.9x; curve not saturated at 2).
//  B: 512 blocks; min over tc, d2 = max(|p|^2+2min,0), sqrt, ticket-reduce.
// min_n |p-t|^2 = |p|^2 + 2*min_n(0.5|t|^2 - p.t): 3 fma + 1 min per pair.
// VALU floor: 549.8M pairs * 4 lane-ops / 78.6e12 = 28 us.

template <int TC>
__global__ __launch_bounds__(THREADS)
__attribute__((amdgpu_waves_per_eu(4, 4)))
void chamfer_partial(const float* __restrict__ shape,
                     const float* __restrict__ tmpl,
                     float* __restrict__ ws,
                     unsigned int* __restrict__ ticket) {
  constexpr int TPC = NPTS / TC;
  __shared__ float4 tile[TPC];

  if (blockIdx.x == 0 && blockIdx.y == 0 && blockIdx.z == 0 && threadIdx.x == 0)
    *ticket = 0u;  // consumed by kernel B (stream-ordered)

  const int tc = blockIdx.x;
  const int b = blockIdx.y;
  const int dir = blockIdx.z;
  const float* Pb = (dir == 0 ? shape : tmpl) + (size_t)b * NPTS * 3;
  const float* Tb = (dir == 0 ? tmpl : shape) + (size_t)b * NPTS * 3;

  // Stage this chunk's targets: 3 float4 global loads -> 4 padded pts + h.
  const float4* T4 = (const float4*)Tb;
  for (int g = threadIdx.x; g < TPC / 4; g += THREADS) {
    float4 a = T4[(tc * (TPC / 4) + g) * 3 + 0];
    float4 c = T4[(tc * (TPC / 4) + g) * 3 + 1];
    float4 d = T4[(tc * (TPC / 4) + g) * 3 + 2];
    const int base = g * 4;
    tile[base + 0] = make_float4(a.x, a.y, a.z,
                                 0.5f * fmaf(a.x, a.x, fmaf(a.y, a.y, a.z * a.z)));
    tile[base + 1] = make_float4(a.w, c.x, c.y,
                                 0.5f * fmaf(a.w, a.w, fmaf(c.x, c.x, c.y * c.y)));
    tile[base + 2] = make_float4(c.z, c.w, d.x,
                                 0.5f * fmaf(c.z, c.z, fmaf(c.w, c.w, d.x * d.x)));
    tile[base + 3] = make_float4(d.y, d.z, d.w,
                                 0.5f * fmaf(d.y, d.y, fmaf(d.z, d.z, d.w * d.w)));
  }
  __syncthreads();

  // Load 16 queries (negated components; |p|^2 handled in kernel B).
  float nx[QP], ny[QP], nz[QP], acc[QP];
  #pragma unroll
  for (int c = 0; c < QP; ++c) {
    const int mq = c * THREADS + threadIdx.x;
    nx[c] = -Pb[3 * mq + 0];
    ny[c] = -Pb[3 * mq + 1];
    nz[c] = -Pb[3 * mq + 2];
    acc[c] = 3.402823466e38f;
  }

  float4 t0 = tile[0], t1 = tile[1], t2 = tile[2], t3 = tile[3];
  #define CHAMFER_STEP(T)                                                      \
    _Pragma("unroll") for (int c = 0; c < QP; ++c)                             \
        acc[c] = fminf(acc[c],                                                 \
            fmaf(nx[c], (T).x, fmaf(ny[c], (T).y, fmaf(nz[c], (T).z, (T).w))));
  for (int n = 0; n < TPC - 4; n += 4) {
    float4 u0 = tile[n + 4], u1 = tile[n + 5], u2 = tile[n + 6], u3 = tile[n + 7];
    CHAMFER_STEP(t0) CHAMFER_STEP(t1) CHAMFER_STEP(t2) CHAMFER_STEP(t3)
    t0 = u0; t1 = u1; t2 = u2; t3 = u3;
  }
  CHAMFER_STEP(t0) CHAMFER_STEP(t1) CHAMFER_STEP(t2) CHAMFER_STEP(t3)
  #undef CHAMFER_STEP

  // ws layout [b][dir][tc][q]: coalesced writes here, coalesced reads in B.
  const int base = ((b * 2 + dir) * TC + tc) << 12;
  #pragma unroll
  for (int c = 0; c < QP; ++c)
    ws[base + c * THREADS + threadIdx.x] = acc[c];
}

template <int TC>
__global__ __launch_bounds__(THREADS) void chamfer_combine(
    const float* __restrict__ shape, const float* __restrict__ tmpl,
    const float* __restrict__ ws, float* __restrict__ partials,
    unsigned int* __restrict__ ticket, float* __restrict__ out) {
  __shared__ float red[4];
  __shared__ bool amLast;
  const int g = blockIdx.x * THREADS + threadIdx.x;  // 0..131071
  const int b = g >> 13;
  const int rem = g & 8191;
  const int dir = rem >> 12;
  const int q = rem & 4095;

  const int base = ((b * 2 + dir) * TC) << 12;
  float m = 3.402823466e38f;
  #pragma unroll
  for (int tc = 0; tc < TC; ++tc) m = fminf(m, ws[base + (tc << 12) + q]);

  const float* Pb = (dir == 0 ? shape : tmpl) + (size_t)b * NPTS * 3;
  const float px = Pb[3 * q + 0], py = Pb[3 * q + 1], pz = Pb[3 * q + 2];
  const float p2 = fmaf(px, px, fmaf(py, py, pz * pz));
  float s = sqrtf(fmaxf(fmaf(2.0f, m, p2), 0.0f));

  #pragma unroll
  for (int off = 32; off > 0; off >>= 1) s += __shfl_down(s, off, 64);
  const int lane = threadIdx.x & 63;
  const int wid = threadIdx.x >> 6;
  if (lane == 0) red[wid] = s;
  __syncthreads();
  if (threadIdx.x == 0) {
    partials[blockIdx.x] = red[0] + red[1] + red[2] + red[3];
    __threadfence();  // release: partial visible before ticket bump
    unsigned int t = atomicAdd(ticket, 1u);
    amLast = (t == (unsigned int)(gridDim.x - 1));
  }
  __syncthreads();
  if (amLast) {
    __threadfence();  // acquire: see all blocks' partials
    float v = partials[threadIdx.x] + partials[threadIdx.x + THREADS];
    #pragma unroll
    for (int off = 32; off > 0; off >>= 1) v += __shfl_down(v, off, 64);
    if (lane == 0) red[wid] = v;
    __syncthreads();
    if (threadIdx.x == 0)
      out[0] = (red[0] + red[1] + red[2] + red[3]) * (0.01f / 16.0f);
  }
}

// ---- Fallback (round-2 single kernel) if ws is too small ----
__global__ __launch_bounds__(THREADS) void chamfer_fallback(
    const float* __restrict__ shape, const float* __restrict__ tmpl,
    float* __restrict__ out) {
  __shared__ float4 tile[NPTS];
  const int b = blockIdx.y;
  const int dir = blockIdx.z;
  const float* Pb = (dir == 0 ? shape : tmpl) + (size_t)b * NPTS * 3;
  const float* Tb = (dir == 0 ? tmpl : shape) + (size_t)b * NPTS * 3;
  const float4* T4 = (const float4*)Tb;
  for (int base = threadIdx.x * 4; base < NPTS; base += THREADS * 4) {
    const int k = base >> 2;
    float4 a = T4[3 * k + 0], c = T4[3 * k + 1], d = T4[3 * k + 2];
    tile[base + 0] = make_float4(a.x, a.y, a.z, 0.5f * fmaf(a.x, a.x, fmaf(a.y, a.y, a.z * a.z)));
    tile[base + 1] = make_float4(a.w, c.x, c.y, 0.5f * fmaf(a.w, a.w, fmaf(c.x, c.x, c.y * c.y)));
    tile[base + 2] = make_float4(c.z, c.w, d.x, 0.5f * fmaf(c.z, c.z, fmaf(c.w, c.w, d.x * d.x)));
    tile[base + 3] = make_float4(d.y, d.z, d.w, 0.5f * fmaf(d.y, d.y, fmaf(d.z, d.z, d.w * d.w)));
  }
  __syncthreads();
  const int m0 = blockIdx.x * (THREADS * 2) + threadIdx.x;
  const int m1 = m0 + THREADS;
  const float qx0 = Pb[3 * m0], qy0 = Pb[3 * m0 + 1], qz0 = Pb[3 * m0 + 2];
  const float qx1 = Pb[3 * m1], qy1 = Pb[3 * m1 + 1], qz1 = Pb[3 * m1 + 2];
  const float nx0 = -qx0, ny0 = -qy0, nz0 = -qz0;
  const float nx1 = -qx1, ny1 = -qy1, nz1 = -qz1;
  const float p20 = fmaf(qx0, qx0, fmaf(qy0, qy0, qz0 * qz0));
  const float p21 = fmaf(qx1, qx1, fmaf(qy1, qy1, qz1 * qz1));
  const float INF = 3.402823466e38f;
  float a00 = INF, a01 = INF, a10 = INF, a11 = INF;
  #pragma unroll 2
  for (int n = 0; n < NPTS; n += 2) {
    float4 t0 = tile[n], t1 = tile[n + 1];
    a00 = fminf(a00, fmaf(nx0, t0.x, fmaf(ny0, t0.y, fmaf(nz0, t0.z, t0.w))));
    a10 = fminf(a10, fmaf(nx1, t0.x, fmaf(ny1, t0.y, fmaf(nz1, t0.z, t0.w))));
    a01 = fminf(a01, fmaf(nx0, t1.x, fmaf(ny0, t1.y, fmaf(nz0, t1.z, t1.w))));
    a11 = fminf(a11, fmaf(nx1, t1.x, fmaf(ny1, t1.y, fmaf(nz1, t1.z, t1.w))));
  }
  float s = sqrtf(fmaxf(fmaf(2.0f, fminf(a00, a01), p20), 0.0f)) +
            sqrtf(fmaxf(fmaf(2.0f, fminf(a10, a11), p21), 0.0f));
  #pragma unroll
  for (int off = 32; off > 0; off >>= 1) s += __shfl_down(s, off, 64);
  __syncthreads();
  float* red = (float*)tile;
  if ((threadIdx.x & 63) == 0) red[threadIdx.x >> 6] = s;
  __syncthreads();
  if (threadIdx.x == 0)
    atomicAdd(out, (red[0] + red[1] + red[2] + red[3]) * (0.01f / 16.0f));
}

extern "C" void kernel_launch(void* const* d_in, const int* in_sizes, int n_in,
                              void* d_out, int out_size, void* d_ws, size_t ws_size,
                              hipStream_t stream) {
  const float* shape = (const float*)d_in[0];
  const float* tmpl = (const float*)d_in[1];
  float* out = (float*)d_out;

  const size_t ws32 = (size_t)NBATCH * 2 * 32 * NPTS * sizeof(float);  // 16 MB
  const size_t ws16 = (size_t)NBATCH * 2 * 16 * NPTS * sizeof(float);  // 8 MB
  const size_t extra = NBLK_B * sizeof(float) + sizeof(unsigned int);
  if (ws_size >= ws32 + extra) {
    float* ws_part = (float*)d_ws;
    float* partials = (float*)((char*)d_ws + ws32);
    unsigned int* ticket = (unsigned int*)(partials + NBLK_B);
    chamfer_partial<32><<<dim3(32, NBATCH, 2), dim3(THREADS), 0, stream>>>(
        shape, tmpl, ws_part, ticket);
    chamfer_combine<32><<<dim3(NBLK_B), dim3(THREADS), 0, stream>>>(
        shape, tmpl, ws_part, partials, ticket, out);
  } else if (ws_size >= ws16 + extra) {
    float* ws_part = (float*)d_ws;
    float* partials = (float*)((char*)d_ws + ws16);
    unsigned int* ticket = (unsigned int*)(partials + NBLK_B);
    chamfer_partial<16><<<dim3(16, NBATCH, 2), dim3(THREADS), 0, stream>>>(
        shape, tmpl, ws_part, ticket);
    chamfer_combine<16><<<dim3(NBLK_B), dim3(THREADS), 0, stream>>>(
        shape, tmpl, ws_part, partials, ticket, out);
  } else {
    hipMemsetAsync(out, 0, sizeof(float) * out_size, stream);
    dim3 grid(NPTS / (THREADS * 2), NBATCH, 2);
    chamfer_fallback<<<grid, dim3(THREADS), 0, stream>>>(shape, tmpl, out);
  }
}

// Round 7
// 91.039 us; speedup vs baseline: 1.3050x; 1.3050x over previous
//
#include <hip/hip_runtime.h>

#define NPTS 4096
#define NBATCH 16
#define THREADS 256
#define QPB 256          // queries per block
#define TCH 1024         // targets per LDS chunk
#define NCH (NPTS / TCH) // 4 chunks
#define REC 24           // ushort stride per 16-slot record (48 B: 2-way conflict free)

typedef __attribute__((ext_vector_type(8))) short short8;
typedef __attribute__((ext_vector_type(4))) float float4v;

static __device__ __forceinline__ unsigned short f2bf(float f) {
  unsigned int u = __builtin_bit_cast(unsigned int, f);
  u = (u + 0x7FFFu + ((u >> 16) & 1u)) >> 16;  // RNE
  return (unsigned short)u;
}
static __device__ __forceinline__ float bf2f(unsigned short h) {
  unsigned int u = ((unsigned int)h) << 16;
  return __builtin_bit_cast(float, u);
}

// Chamfer, fp32, B=16, N=M=4096, d=3, via bf16-split MFMA.
// d2 = |p|^2 + (-2p.t + |t|^2); the bracket is a K=11 dot product evaluated by
// mfma_f32_16x16x32_bf16 (hi/lo split: hh+hl+lh per coord + |t|^2 hi/lo vs 1).
// K-slot layout (A = query u=-2p, B = target t):
//   A: [uhx,uhx,ulx, uhy,uhy,uly, uhz,uhz,ulz, 1,1, 0..]   (k = quad*8+j)
//   B: [thx,tlx,thx, thy,tly,thy, thz,tlz,thz, t2h,t2l, 0..]
// Residual (ul*tl + split rounding) ~5e-5 on d2 -- absmax budget is 0.256.
// Per 16x16 tile: 1 MFMA + 4 v_min (C=0 input; min in VALU since MFMA only
// accumulates with +). VALU floor 6.8us, MFMA floor ~4.3us, LDS ~3.4us.
// Grid (16 qchunks, 16 batch, 2 dir) = 512 blocks; each block: 256 queries,
// loops 4 LDS chunks of 1024 targets. Wave holds 4 A-frags (64 queries).
__global__ __launch_bounds__(THREADS, 2) void chamfer_mfma(
    const float* __restrict__ shape, const float* __restrict__ tmpl,
    float* __restrict__ out) {
  __shared__ unsigned short tgt[TCH * REC];  // 48 KB
  __shared__ unsigned short qry[QPB * REC];  // 12 KB
  __shared__ float p2s[QPB];                 // 1 KB
  __shared__ float redbuf[4];

  const int qc = blockIdx.x;
  const int b = blockIdx.y;
  const int dir = blockIdx.z;
  const float* Pb = (dir == 0 ? shape : tmpl) + (size_t)b * NPTS * 3;
  const float* Tb = (dir == 0 ? tmpl : shape) + (size_t)b * NPTS * 3;

  const int tid = threadIdx.x;
  const int lane = tid & 63;
  const int wave = tid >> 6;
  const int quad = lane >> 4;
  const int n15 = lane & 15;
  const bool kactive = (quad < 2);  // k=quad*8+j covers 0..15 only for quads 0,1

  // ---- Stage 256 queries: u=-2p hi/lo split record + |p|^2 ----
  {
    const int qg = qc * QPB + tid;
    const float px = Pb[3 * qg + 0], py = Pb[3 * qg + 1], pz = Pb[3 * qg + 2];
    const float ux = -2.0f * px, uy = -2.0f * py, uz = -2.0f * pz;
    const unsigned short hx = f2bf(ux), hy = f2bf(uy), hz = f2bf(uz);
    const unsigned short lx = f2bf(ux - bf2f(hx)), ly = f2bf(uy - bf2f(hy)),
                         lz = f2bf(uz - bf2f(hz));
    const unsigned short ONE = 0x3F80;
    short8 v0, v1;
    v0[0] = hx; v0[1] = hx; v0[2] = lx; v0[3] = hy;
    v0[4] = hy; v0[5] = ly; v0[6] = hz; v0[7] = hz;
    v1[0] = lz; v1[1] = ONE; v1[2] = ONE; v1[3] = 0;
    v1[4] = 0;  v1[5] = 0;  v1[6] = 0;  v1[7] = 0;
    *(short8*)&qry[tid * REC] = v0;
    *(short8*)&qry[tid * REC + 8] = v1;
    p2s[tid] = fmaf(px, px, fmaf(py, py, pz * pz));
  }
  __syncthreads();

  // ---- Load 4 A-frags (wave covers queries wave*64 .. wave*64+63) ----
  short8 af[4];
  #pragma unroll
  for (int t = 0; t < 4; ++t) {
    const int q = (wave * 4 + t) * 16 + n15;
    short8 v = {};
    if (kactive) v = *(const short8*)&qry[q * REC + quad * 8];
    af[t] = v;
  }

  const float INF = 3.402823466e38f;
  float4v mins[4];
  #pragma unroll
  for (int t = 0; t < 4; ++t) mins[t] = (float4v){INF, INF, INF, INF};
  const float4v zero4 = {0.0f, 0.0f, 0.0f, 0.0f};

  const float4* T4 = (const float4*)Tb;
  for (int ch = 0; ch < NCH; ++ch) {
    __syncthreads();  // previous chunk's reads complete
    // ---- Stage 1024 targets (4 per thread via 3 float4 loads) ----
    {
      const int g = ch * (TCH / 4) + tid;  // global group of 4 targets
      const float4 a = T4[g * 3 + 0];
      const float4 c = T4[g * 3 + 1];
      const float4 d = T4[g * 3 + 2];
      const float X[4] = {a.x, a.w, c.z, d.y};
      const float Y[4] = {a.y, c.x, c.w, d.z};
      const float Z[4] = {a.z, c.y, d.x, d.w};
      #pragma unroll
      for (int p = 0; p < 4; ++p) {
        const float x = X[p], y = Y[p], z = Z[p];
        const float t2 = fmaf(x, x, fmaf(y, y, z * z));
        const unsigned short hx = f2bf(x), hy = f2bf(y), hz = f2bf(z);
        const unsigned short lx = f2bf(x - bf2f(hx)), ly = f2bf(y - bf2f(hy)),
                             lz = f2bf(z - bf2f(hz));
        const unsigned short h2 = f2bf(t2), l2 = f2bf(t2 - bf2f(h2));
        short8 v0, v1;
        v0[0] = hx; v0[1] = lx; v0[2] = hx; v0[3] = hy;
        v0[4] = ly; v0[5] = hy; v0[6] = hz; v0[7] = lz;
        v1[0] = hz; v1[1] = h2; v1[2] = l2; v1[3] = 0;
        v1[4] = 0;  v1[5] = 0;  v1[6] = 0;  v1[7] = 0;
        unsigned short* dst = &tgt[(tid * 4 + p) * REC];
        *(short8*)dst = v0;
        *(short8*)(dst + 8) = v1;
      }
    }
    __syncthreads();

    // ---- 64 target tiles: 1 ds_read_b128 -> 4 MFMA + 16 v_min ----
    const unsigned short* bbase = &tgt[n15 * REC + quad * 8];
    #pragma unroll 4
    for (int tn = 0; tn < TCH / 16; ++tn) {
      short8 bf = {};
      if (kactive) bf = *(const short8*)(bbase + tn * (16 * REC));
      #pragma unroll
      for (int t = 0; t < 4; ++t) {
        float4v d2 = __builtin_amdgcn_mfma_f32_16x16x32_bf16(af[t], bf, zero4, 0, 0, 0);
        mins[t].x = fminf(mins[t].x, d2.x);
        mins[t].y = fminf(mins[t].y, d2.y);
        mins[t].z = fminf(mins[t].z, d2.z);
        mins[t].w = fminf(mins[t].w, d2.w);
      }
    }
  }

  // ---- Cross-lane min over the 16 cols (lanes sharing quad) ----
  #pragma unroll
  for (int t = 0; t < 4; ++t) {
    #pragma unroll
    for (int m = 1; m <= 8; m <<= 1) {
      mins[t].x = fminf(mins[t].x, __shfl_xor(mins[t].x, m, 64));
      mins[t].y = fminf(mins[t].y, __shfl_xor(mins[t].y, m, 64));
      mins[t].z = fminf(mins[t].z, __shfl_xor(mins[t].z, m, 64));
      mins[t].w = fminf(mins[t].w, __shfl_xor(mins[t].w, m, 64));
    }
  }

  // ---- Epilogue: d = sqrt(max(min + |p|^2, 0)); reduce; one atomic/block ----
  float s = 0.0f;
  if (n15 == 0) {
    #pragma unroll
    for (int t = 0; t < 4; ++t) {
      const int qb = (wave * 4 + t) * 16 + quad * 4;  // row = quad*4 + reg
      s += sqrtf(fmaxf(mins[t].x + p2s[qb + 0], 0.0f));
      s += sqrtf(fmaxf(mins[t].y + p2s[qb + 1], 0.0f));
      s += sqrtf(fmaxf(mins[t].z + p2s[qb + 2], 0.0f));
      s += sqrtf(fmaxf(mins[t].w + p2s[qb + 3], 0.0f));
    }
  }
  s += __shfl_xor(s, 16, 64);
  s += __shfl_xor(s, 32, 64);
  if (lane == 0) redbuf[wave] = s;
  __syncthreads();
  if (tid == 0) {
    // out = 0.01 * mean over 16 batches of per-batch chamfer sums
    atomicAdd(out, (redbuf[0] + redbuf[1] + redbuf[2] + redbuf[3]) * (0.01f / 16.0f));
  }
}

extern "C" void kernel_launch(void* const* d_in, const int* in_sizes, int n_in,
                              void* d_out, int out_size, void* d_ws, size_t ws_size,
                              hipStream_t stream) {
  const float* shape = (const float*)d_in[0];
  const float* tmpl = (const float*)d_in[1];
  float* out = (float*)d_out;

  // d_out is poisoned to 0xAA before every timed launch; atomics need zeros.
  hipMemsetAsync(out, 0, sizeof(float) * out_size, stream);

  dim3 grid(NPTS / QPB, NBATCH, 2);
  chamfer_mfma<<<grid, dim3(THREADS), 0, stream>>>(shape, tmpl, out);
}

// Round 8
// 81.876 us; speedup vs baseline: 1.4510x; 1.1119x over previous
//
#include <hip/hip_runtime.h>

#define NPTS 4096
#define NBATCH 16
#define THREADS 256
#define QPB 256          // queries per block
#define TCH 1024         // targets per LDS chunk
#define NCH (NPTS / TCH) // 4 chunks

typedef __attribute__((ext_vector_type(8))) short short8;
typedef __attribute__((ext_vector_type(16))) float float16v;

static __device__ __forceinline__ unsigned short f2bf(float f) {
  unsigned int u = __builtin_bit_cast(unsigned int, f);
  u = (u + 0x7FFFu + ((u >> 16) & 1u)) >> 16;  // RNE
  return (unsigned short)u;
}
static __device__ __forceinline__ float bf2f(unsigned short h) {
  unsigned int u = ((unsigned int)h) << 16;
  return __builtin_bit_cast(float, u);
}
// Swizzled ushort offset of half-record h of target j. Base = 32B flat records;
// XOR of bits 3..5 (16B-block within 128B) keyed by bits 6..8 -> both the
// staging writes (j = 4*tid+p) and the B-frag reads (j = T*32 + (lane&31))
// cover 128B groups with all-distinct 16B blocks => conflict-free.
static __device__ __forceinline__ int toff(int j, int h) {
  return (j * 16 + h * 8) ^ (((j >> 2) & 7) << 3);
}

// Chamfer, fp32, B=16, N=M=4096, d=3, via bf16-split 32x32x16 MFMA.
// d2 = |p|^2 + (-2p.t + |t|^2); bracket = K=11 dot product (hi/lo split).
//   A (query u=-2p): [uhx,uhx,ulx, uhy,uhy,uly, uhz,uhz,ulz, 1,1, 0*5]
//   B (target t):    [thx,tlx,thx, thy,tly,thy, thz,tlz,thz, t2h,t2l, 0*5]
// (K-slot content byte-identical to round 7's absmax=0.0 kernel; only the
//  MFMA shape/layout changed: 32x32x16 uses 11/16 K-slots vs 11/32, all 64
//  lanes active: m|n=lane&31, k=(lane>>5)*8+j; C/D row=(r&3)+8*(r>>2)+4*kg.)
// Per 32-target tile-pair: 2 ds_read_b128, 4 MFMA, 32 v_min3 (2 d2 per min3).
// Grid (16,16,2)=512 blocks, 2 blocks/CU, 2 waves/SIMD; wave owns 64 queries.
__global__ __launch_bounds__(THREADS)
__attribute__((amdgpu_waves_per_eu(2, 2)))
void chamfer_mfma(const float* __restrict__ shape,
                  const float* __restrict__ tmpl,
                  float* __restrict__ out) {
  __shared__ unsigned short tgt[TCH * 16];  // 32 KB, swizzled flat records
  __shared__ unsigned short qry[QPB * 16];  // 8 KB, flat records
  __shared__ float p2s[QPB];                // 1 KB
  __shared__ float redbuf[4];

  const int qc = blockIdx.x;
  const int b = blockIdx.y;
  const int dir = blockIdx.z;
  const float* Pb = (dir == 0 ? shape : tmpl) + (size_t)b * NPTS * 3;
  const float* Tb = (dir == 0 ? tmpl : shape) + (size_t)b * NPTS * 3;

  const int tid = threadIdx.x;
  const int lane = tid & 63;
  const int wave = tid >> 6;
  const int n = lane & 31;   // MFMA row/col index
  const int kg = lane >> 5;  // K-group: k = kg*8 + j

  // ---- Stage 256 queries: u=-2p hi/lo split record + |p|^2 ----
  {
    const int qg = qc * QPB + tid;
    const float px = Pb[3 * qg + 0], py = Pb[3 * qg + 1], pz = Pb[3 * qg + 2];
    const float ux = -2.0f * px, uy = -2.0f * py, uz = -2.0f * pz;
    const unsigned short hx = f2bf(ux), hy = f2bf(uy), hz = f2bf(uz);
    const unsigned short lx = f2bf(ux - bf2f(hx)), ly = f2bf(uy - bf2f(hy)),
                         lz = f2bf(uz - bf2f(hz));
    const unsigned short ONE = 0x3F80;
    short8 v0, v1;
    v0[0] = hx; v0[1] = hx; v0[2] = lx; v0[3] = hy;
    v0[4] = hy; v0[5] = ly; v0[6] = hz; v0[7] = hz;
    v1[0] = lz; v1[1] = ONE; v1[2] = ONE; v1[3] = 0;
    v1[4] = 0;  v1[5] = 0;  v1[6] = 0;  v1[7] = 0;
    *(short8*)&qry[tid * 16] = v0;
    *(short8*)&qry[tid * 16 + 8] = v1;
    p2s[tid] = fmaf(px, px, fmaf(py, py, pz * pz));
  }
  __syncthreads();

  // ---- A-frags: 2 row-tiles of 32 queries (wave covers 64 queries) ----
  const short8 af0 = *(const short8*)&qry[(wave * 64 + n) * 16 + kg * 8];
  const short8 af1 = *(const short8*)&qry[(wave * 64 + 32 + n) * 16 + kg * 8];

  const float INF = 3.402823466e38f;
  float acc0[16], acc1[16];
  #pragma unroll
  for (int r = 0; r < 16; ++r) { acc0[r] = INF; acc1[r] = INF; }

  const float4* T4 = (const float4*)Tb;
  for (int ch = 0; ch < NCH; ++ch) {
    __syncthreads();  // previous chunk's reads complete
    // ---- Stage 1024 targets (4/thread: 3 float4 loads -> swizzled records) ----
    {
      const int g = ch * (TCH / 4) + tid;
      const float4 a = T4[g * 3 + 0];
      const float4 c = T4[g * 3 + 1];
      const float4 d = T4[g * 3 + 2];
      const float X[4] = {a.x, a.w, c.z, d.y};
      const float Y[4] = {a.y, c.x, c.w, d.z};
      const float Z[4] = {a.z, c.y, d.x, d.w};
      #pragma unroll
      for (int p = 0; p < 4; ++p) {
        const float x = X[p], y = Y[p], z = Z[p];
        const float t2 = fmaf(x, x, fmaf(y, y, z * z));
        const unsigned short hx = f2bf(x), hy = f2bf(y), hz = f2bf(z);
        const unsigned short lx = f2bf(x - bf2f(hx)), ly = f2bf(y - bf2f(hy)),
                             lz = f2bf(z - bf2f(hz));
        const unsigned short h2 = f2bf(t2), l2 = f2bf(t2 - bf2f(h2));
        short8 v0, v1;
        v0[0] = hx; v0[1] = lx; v0[2] = hx; v0[3] = hy;
        v0[4] = ly; v0[5] = hy; v0[6] = hz; v0[7] = lz;
        v1[0] = hz; v1[1] = h2; v1[2] = l2; v1[3] = 0;
        v1[4] = 0;  v1[5] = 0;  v1[6] = 0;  v1[7] = 0;
        const int j = tid * 4 + p;
        *(short8*)&tgt[toff(j, 0)] = v0;
        *(short8*)&tgt[toff(j, 1)] = v1;
      }
    }
    __syncthreads();

    // ---- 32 target tiles as 16 pairs: 2 reads -> 4 MFMA -> 32 min3 ----
    for (int tp = 0; tp < TCH / 64; ++tp) {
      const short8 b0 = *(const short8*)&tgt[toff(tp * 64 + n, kg)];
      const short8 b1 = *(const short8*)&tgt[toff(tp * 64 + 32 + n, kg)];
      const float16v z = {};
      float16v d00 = __builtin_amdgcn_mfma_f32_32x32x16_bf16(af0, b0, z, 0, 0, 0);
      float16v d10 = __builtin_amdgcn_mfma_f32_32x32x16_bf16(af1, b0, z, 0, 0, 0);
      float16v d01 = __builtin_amdgcn_mfma_f32_32x32x16_bf16(af0, b1, z, 0, 0, 0);
      float16v d11 = __builtin_amdgcn_mfma_f32_32x32x16_bf16(af1, b1, z, 0, 0, 0);
      #pragma unroll
      for (int r = 0; r < 16; ++r)
        acc0[r] = fminf(fminf(d00[r], d01[r]), acc0[r]);  // v_min3_f32
      #pragma unroll
      for (int r = 0; r < 16; ++r)
        acc1[r] = fminf(fminf(d10[r], d11[r]), acc1[r]);
    }
  }

  // ---- Min across the 32 cols (lanes within kg group share col set) ----
  #pragma unroll
  for (int m = 1; m <= 16; m <<= 1) {
    #pragma unroll
    for (int r = 0; r < 16; ++r) {
      acc0[r] = fminf(acc0[r], __shfl_xor(acc0[r], m, 64));
      acc1[r] = fminf(acc1[r], __shfl_xor(acc1[r], m, 64));
    }
  }

  // ---- Epilogue: d = sqrt(max(min + |p|^2, 0)); reduce; one atomic/block ----
  float s = 0.0f;
  if (n == 0) {  // lanes 0 (kg=0) and 32 (kg=1): disjoint row sets
    const int qb = wave * 64;
    #pragma unroll
    for (int r = 0; r < 16; ++r) {
      const int row = (r & 3) + 8 * (r >> 2) + 4 * kg;
      s += sqrtf(fmaxf(acc0[r] + p2s[qb + row], 0.0f));
      s += sqrtf(fmaxf(acc1[r] + p2s[qb + 32 + row], 0.0f));
    }
  }
  s += __shfl_xor(s, 32, 64);  // combine kg=0 and kg=1 partial sums
  if (lane == 0) redbuf[wave] = s;
  __syncthreads();
  if (tid == 0) {
    // out = 0.01 * mean over 16 batches of per-batch chamfer sums
    atomicAdd(out, (redbuf[0] + redbuf[1] + redbuf[2] + redbuf[3]) * (0.01f / 16.0f));
  }
}

extern "C" void kernel_launch(void* const* d_in, const int* in_sizes, int n_in,
                              void* d_out, int out_size, void* d_ws, size_t ws_size,
                              hipStream_t stream) {
  const float* shape = (const float*)d_in[0];
  const float* tmpl = (const float*)d_in[1];
  float* out = (float*)d_out;

  // d_out is poisoned to 0xAA before every timed launch; atomics need zeros.
  hipMemsetAsync(out, 0, sizeof(float) * out_size, stream);

  dim3 grid(NPTS / QPB, NBATCH, 2);
  chamfer_mfma<<<grid, dim3(THREADS), 0, stream>>>(shape, tmpl, out);
}